// Round 5
// baseline (576.079 us; speedup 1.0000x reference)
//
#include <hip/hip_runtime.h>
#include <hip/hip_cooperative_groups.h>

namespace cg = cooperative_groups;

// Causal linear attention (ELU+1), chunked prefix-scan.
// Preferred path: ONE cooperative kernel (3 phases, 2 grid syncs, 4 blocks/CU
// exactly co-resident). Fallback path (if cooperative launch is refused):
// the round-3 proven 3-kernel pipeline.
//
// R4 lesson: hipLaunchCooperativeKernel return was unchecked; a refused launch
// leaves d_out zeroed -> absmax == max|ref|. Now checked + fallback, and
// __threadfence() (device-scope release) precedes each grid.sync().

#define BQ 2
#define TT 2048
#define HH 16
#define DD 64
#define CC 64
#define NC (TT / CC)      // 32 chunks per (b,h)
#define BH (BQ * HH)      // 32
#define NCH (BH * NC)     // 1024 chunk-blocks
#define LDP 68            // LDS row stride (floats)

#define F4C(v, i) ((i) == 0 ? (v).x : (i) == 1 ? (v).y : (i) == 2 ? (v).z : (v).w)

__device__ __forceinline__ float phi_f(float x) {
    return x > 0.f ? x + 1.f : __expf(x);   // elu(x)+1
}

// ======================= fused cooperative kernel =======================
__global__ __launch_bounds__(256, 4) void k_fused(const float* __restrict__ Q,
                                                  const float* __restrict__ K,
                                                  const float* __restrict__ V,
                                                  float* __restrict__ wsS,
                                                  float* __restrict__ wsZ,
                                                  float* __restrict__ O) {
    __shared__ float bufA[CC][LDP];   // A: phiK   | C: phiQ, later V
    __shared__ float bufB[CC][LDP];   // A: V      | C: phiK, later scores
    __shared__ float zp[DD];

    cg::grid_group grid = cg::this_grid();

    const int cid = blockIdx.x;
    const int bh = cid / NC, c = cid % NC;
    const int b = bh / HH, h = bh % HH;
    const int t0 = c * CC;
    const int tid = threadIdx.x;
    const int d0 = (tid >> 4) << 2;
    const int e0 = (tid & 15) << 2;

    // ---------------- Phase A: per-chunk delta ----------------
#pragma unroll
    for (int w = 0; w < 4; ++w) {
        const int idx = tid + (w << 8);
        const int r = idx >> 4, q4 = (idx & 15) << 2;
        const int g = (((b * TT + t0 + r) * HH + h) << 6) + q4;
        float4 kv = *(const float4*)(K + g);
        kv.x = phi_f(kv.x); kv.y = phi_f(kv.y); kv.z = phi_f(kv.z); kv.w = phi_f(kv.w);
        *(float4*)&bufA[r][q4] = kv;
        *(float4*)&bufB[r][q4] = *(const float4*)(V + g);
    }
    __syncthreads();
    {
        float acc[4][4] = {};
        float zac[4] = {};
#pragma unroll 8
        for (int t = 0; t < CC; ++t) {
            const float4 a = *(const float4*)&bufA[t][d0];
            const float4 vb = *(const float4*)&bufB[t][e0];
            acc[0][0] += a.x * vb.x; acc[0][1] += a.x * vb.y; acc[0][2] += a.x * vb.z; acc[0][3] += a.x * vb.w;
            acc[1][0] += a.y * vb.x; acc[1][1] += a.y * vb.y; acc[1][2] += a.y * vb.z; acc[1][3] += a.y * vb.w;
            acc[2][0] += a.z * vb.x; acc[2][1] += a.z * vb.y; acc[2][2] += a.z * vb.z; acc[2][3] += a.z * vb.w;
            acc[3][0] += a.w * vb.x; acc[3][1] += a.w * vb.y; acc[3][2] += a.w * vb.z; acc[3][3] += a.w * vb.w;
            zac[0] += a.x; zac[1] += a.y; zac[2] += a.z; zac[3] += a.w;
        }
        float* S = wsS + (size_t)cid * (DD * DD);
#pragma unroll
        for (int i = 0; i < 4; ++i)
            *(float4*)(S + (d0 + i) * DD + e0) =
                make_float4(acc[i][0], acc[i][1], acc[i][2], acc[i][3]);
        if (e0 == 0)
            *(float4*)(wsZ + cid * DD + d0) =
                make_float4(zac[0], zac[1], zac[2], zac[3]);
    }

    __threadfence();
    grid.sync();

    // ---------------- Phase B: exclusive prefix over chunks ----------------
    {
        const int sbh = blockIdx.x >> 5;
        const int seg = blockIdx.x & 31;
        if (tid < 128) {
            float* p = wsS + (size_t)sbh * NC * (DD * DD) + (seg << 7) + tid;
            float run = 0.f;
#pragma unroll
            for (int cc = 0; cc < NC; ++cc) {
                const float d = p[(size_t)cc * (DD * DD)];
                p[(size_t)cc * (DD * DD)] = run;
                run += d;
            }
        } else if (tid < 192 && seg == 0) {
            const int d = tid - 128;
            float* p = wsZ + sbh * NC * DD + d;
            float run = 0.f;
#pragma unroll
            for (int cc = 0; cc < NC; ++cc) {
                const float dv = p[cc * DD];
                p[cc * DD] = run;
                run += dv;
            }
        }
    }

    __threadfence();
    grid.sync();

    // ---------------- Phase C: outputs ----------------
    float4 vreg[4];
#pragma unroll
    for (int w = 0; w < 4; ++w) {
        const int idx = tid + (w << 8);
        const int r = idx >> 4, q4 = (idx & 15) << 2;
        const int g = (((b * TT + t0 + r) * HH + h) << 6) + q4;
        vreg[w] = *(const float4*)(V + g);
        float4 qv = *(const float4*)(Q + g);
        qv.x = phi_f(qv.x); qv.y = phi_f(qv.y); qv.z = phi_f(qv.z); qv.w = phi_f(qv.w);
        *(float4*)&bufA[r][q4] = qv;
        float4 kv = *(const float4*)(K + g);
        kv.x = phi_f(kv.x); kv.y = phi_f(kv.y); kv.z = phi_f(kv.z); kv.w = phi_f(kv.w);
        *(float4*)&bufB[r][q4] = kv;
    }
    if (tid < 16) ((float4*)zp)[tid] = ((const float4*)(wsZ + cid * DD))[tid];
    __syncthreads();

    const int tt = d0;

    float den4[4];
    {
        float a[4][4] = {};
#pragma unroll 4
        for (int d = 0; d < DD; d += 4) {
            float4 qr[4], kr[4];
#pragma unroll
            for (int i = 0; i < 4; ++i) qr[i] = *(const float4*)&bufA[tt + i][d];
#pragma unroll
            for (int j = 0; j < 4; ++j) kr[j] = *(const float4*)&bufB[e0 + j][d];
#pragma unroll
            for (int i = 0; i < 4; ++i)
#pragma unroll
                for (int j = 0; j < 4; ++j)
                    a[i][j] += qr[i].x * kr[j].x + qr[i].y * kr[j].y +
                               qr[i].z * kr[j].z + qr[i].w * kr[j].w;
        }
#pragma unroll
        for (int i = 0; i < 4; ++i) {
#pragma unroll
            for (int j = 0; j < 4; ++j)
                if (e0 + j > tt + i) a[i][j] = 0.f;
            den4[i] = a[i][0] + a[i][1] + a[i][2] + a[i][3];
        }
#pragma unroll
        for (int m = 1; m < 16; m <<= 1)
#pragma unroll
            for (int i = 0; i < 4; ++i)
                den4[i] += __shfl_xor(den4[i], m, 64);

        __syncthreads();
#pragma unroll
        for (int i = 0; i < 4; ++i)
            *(float4*)&bufB[tt + i][e0] =
                make_float4(a[i][0], a[i][1], a[i][2], a[i][3]);
    }

    float o[4][4] = {};
    float dint[4] = {};
    {
        const float* Sg = wsS + (size_t)cid * (DD * DD);
#pragma unroll 4
        for (int d = 0; d < DD; d += 4) {
            float4 qr[4], sr[4];
#pragma unroll
            for (int i = 0; i < 4; ++i) qr[i] = *(const float4*)&bufA[tt + i][d];
#pragma unroll
            for (int r = 0; r < 4; ++r)
                sr[r] = *(const float4*)(Sg + (d + r) * DD + e0);
            const float4 z4 = *(const float4*)&zp[d];
#pragma unroll
            for (int i = 0; i < 4; ++i) {
                const float4 qv = qr[i];
                o[i][0] += qv.x * sr[0].x + qv.y * sr[1].x + qv.z * sr[2].x + qv.w * sr[3].x;
                o[i][1] += qv.x * sr[0].y + qv.y * sr[1].y + qv.z * sr[2].y + qv.w * sr[3].y;
                o[i][2] += qv.x * sr[0].z + qv.y * sr[1].z + qv.z * sr[2].z + qv.w * sr[3].z;
                o[i][3] += qv.x * sr[0].w + qv.y * sr[1].w + qv.z * sr[2].w + qv.w * sr[3].w;
                dint[i] += qv.x * z4.x + qv.y * z4.y + qv.z * z4.z + qv.w * z4.w;
            }
        }
    }

    __syncthreads();
#pragma unroll
    for (int w = 0; w < 4; ++w) {
        const int idx = tid + (w << 8);
        *(float4*)&bufA[idx >> 4][(idx & 15) << 2] = vreg[w];
    }
    __syncthreads();

    const int nq = (tt >> 2) + 1;
    for (int sq = 0; sq < nq; ++sq) {
        float4 ar[4];
#pragma unroll
        for (int i = 0; i < 4; ++i) ar[i] = *(const float4*)&bufB[tt + i][sq << 2];
#pragma unroll
        for (int ss = 0; ss < 4; ++ss) {
            const float4 vv = *(const float4*)&bufA[(sq << 2) + ss][e0];
#pragma unroll
            for (int i = 0; i < 4; ++i) {
                const float av = F4C(ar[i], ss);
                o[i][0] += av * vv.x; o[i][1] += av * vv.y;
                o[i][2] += av * vv.z; o[i][3] += av * vv.w;
            }
        }
    }

#pragma unroll
    for (int i = 0; i < 4; ++i) {
        const float den = dint[i] + den4[i] + 1e-6f;
        const float inv = 1.0f / den;
        const int g = (((b * TT + t0 + tt + i) * HH + h) << 6) + e0;
        *(float4*)(O + g) = make_float4(o[i][0] * inv, o[i][1] * inv,
                                        o[i][2] * inv, o[i][3] * inv);
    }
}

// ======================= fallback: round-3 proven 3-kernel path =======================
__global__ __launch_bounds__(256, 4) void k_state(const float* __restrict__ K,
                                                  const float* __restrict__ V,
                                                  float* __restrict__ wsS,
                                                  float* __restrict__ wsZ) {
    __shared__ float pk[CC][LDP];
    __shared__ float pv[CC][LDP];

    const int cid = blockIdx.x;
    const int bh = cid / NC, c = cid % NC;
    const int b = bh / HH, h = bh % HH;
    const int t0 = c * CC;
    const int tid = threadIdx.x;

#pragma unroll
    for (int w = 0; w < 4; ++w) {
        const int idx = tid + (w << 8);
        const int r = idx >> 4, q4 = (idx & 15) << 2;
        const int g = (((b * TT + t0 + r) * HH + h) << 6) + q4;
        float4 kv = *(const float4*)(K + g);
        kv.x = phi_f(kv.x); kv.y = phi_f(kv.y); kv.z = phi_f(kv.z); kv.w = phi_f(kv.w);
        *(float4*)&pk[r][q4] = kv;
        *(float4*)&pv[r][q4] = *(const float4*)(V + g);
    }
    __syncthreads();

    const int d0 = (tid >> 4) << 2;
    const int e0 = (tid & 15) << 2;
    float acc[4][4] = {};
    float zac[4] = {};
#pragma unroll 8
    for (int t = 0; t < CC; ++t) {
        const float4 a = *(const float4*)&pk[t][d0];
        const float4 vb = *(const float4*)&pv[t][e0];
        acc[0][0] += a.x * vb.x; acc[0][1] += a.x * vb.y; acc[0][2] += a.x * vb.z; acc[0][3] += a.x * vb.w;
        acc[1][0] += a.y * vb.x; acc[1][1] += a.y * vb.y; acc[1][2] += a.y * vb.z; acc[1][3] += a.y * vb.w;
        acc[2][0] += a.z * vb.x; acc[2][1] += a.z * vb.y; acc[2][2] += a.z * vb.z; acc[2][3] += a.z * vb.w;
        acc[3][0] += a.w * vb.x; acc[3][1] += a.w * vb.y; acc[3][2] += a.w * vb.z; acc[3][3] += a.w * vb.w;
        zac[0] += a.x; zac[1] += a.y; zac[2] += a.z; zac[3] += a.w;
    }

    float* S = wsS + (size_t)cid * (DD * DD);
#pragma unroll
    for (int i = 0; i < 4; ++i)
        *(float4*)(S + (d0 + i) * DD + e0) =
            make_float4(acc[i][0], acc[i][1], acc[i][2], acc[i][3]);
    if (e0 == 0)
        *(float4*)(wsZ + cid * DD + d0) = make_float4(zac[0], zac[1], zac[2], zac[3]);
}

__global__ __launch_bounds__(256) void k_scan(float* __restrict__ wsS,
                                              float* __restrict__ wsZ) {
    const int blk = blockIdx.x, tid = threadIdx.x;
    if (blk < 512) {
        const int bh = blk >> 4;
        const int off = ((blk & 15) << 8) + tid;
        float* p = wsS + (size_t)bh * NC * (DD * DD) + off;
        float run = 0.f;
#pragma unroll
        for (int c = 0; c < NC; ++c) {
            const float d = p[(size_t)c * (DD * DD)];
            p[(size_t)c * (DD * DD)] = run;
            run += d;
        }
    } else {
        const int zi = ((blk - 512) << 8) + tid;
        const int bh = zi >> 6, d = zi & 63;
        float* p = wsZ + bh * NC * DD + d;
        float run = 0.f;
#pragma unroll
        for (int c = 0; c < NC; ++c) {
            const float dv = p[c * DD];
            p[c * DD] = run;
            run += dv;
        }
    }
}

__global__ __launch_bounds__(256, 4) void k_out(const float* __restrict__ Q,
                                                const float* __restrict__ K,
                                                const float* __restrict__ V,
                                                const float* __restrict__ wsS,
                                                const float* __restrict__ wsZ,
                                                float* __restrict__ O) {
    __shared__ float bufA[CC][LDP];
    __shared__ float bufB[CC][LDP];
    __shared__ float Sp[DD * DD];
    __shared__ float zp[DD];

    const int cid = blockIdx.x;
    const int bh = cid / NC, c = cid % NC;
    const int b = bh / HH, h = bh % HH;
    const int t0 = c * CC;
    const int tid = threadIdx.x;

    float4 vreg[4];
#pragma unroll
    for (int w = 0; w < 4; ++w) {
        const int idx = tid + (w << 8);
        const int r = idx >> 4, q4 = (idx & 15) << 2;
        const int g = (((b * TT + t0 + r) * HH + h) << 6) + q4;
        vreg[w] = *(const float4*)(V + g);
        float4 qv = *(const float4*)(Q + g);
        qv.x = phi_f(qv.x); qv.y = phi_f(qv.y); qv.z = phi_f(qv.z); qv.w = phi_f(qv.w);
        *(float4*)&bufA[r][q4] = qv;
        float4 kv = *(const float4*)(K + g);
        kv.x = phi_f(kv.x); kv.y = phi_f(kv.y); kv.z = phi_f(kv.z); kv.w = phi_f(kv.w);
        *(float4*)&bufB[r][q4] = kv;
    }
    {
        const float4* Sg = (const float4*)(wsS + (size_t)cid * (DD * DD));
        float4* Sl = (float4*)Sp;
#pragma unroll
        for (int w = 0; w < 4; ++w) Sl[tid + (w << 8)] = Sg[tid + (w << 8)];
        if (tid < 16) ((float4*)zp)[tid] = ((const float4*)(wsZ + cid * DD))[tid];
    }
    __syncthreads();

    const int tt = (tid >> 4) << 2;
    const int e0 = (tid & 15) << 2;

    float den4[4];
    {
        float a[4][4] = {};
#pragma unroll 4
        for (int d = 0; d < DD; d += 4) {
            float4 qr[4], kr[4];
#pragma unroll
            for (int i = 0; i < 4; ++i) qr[i] = *(const float4*)&bufA[tt + i][d];
#pragma unroll
            for (int j = 0; j < 4; ++j) kr[j] = *(const float4*)&bufB[e0 + j][d];
#pragma unroll
            for (int i = 0; i < 4; ++i)
#pragma unroll
                for (int j = 0; j < 4; ++j)
                    a[i][j] += qr[i].x * kr[j].x + qr[i].y * kr[j].y +
                               qr[i].z * kr[j].z + qr[i].w * kr[j].w;
        }
#pragma unroll
        for (int i = 0; i < 4; ++i) {
#pragma unroll
            for (int j = 0; j < 4; ++j)
                if (e0 + j > tt + i) a[i][j] = 0.f;
            den4[i] = a[i][0] + a[i][1] + a[i][2] + a[i][3];
        }
#pragma unroll
        for (int m = 1; m < 16; m <<= 1)
#pragma unroll
            for (int i = 0; i < 4; ++i)
                den4[i] += __shfl_xor(den4[i], m, 64);

        __syncthreads();
#pragma unroll
        for (int i = 0; i < 4; ++i)
            *(float4*)&bufB[tt + i][e0] =
                make_float4(a[i][0], a[i][1], a[i][2], a[i][3]);
    }

    float o[4][4] = {};
    float dint[4] = {};
#pragma unroll 4
    for (int d = 0; d < DD; d += 4) {
        float4 qr[4], sr[4];
#pragma unroll
        for (int i = 0; i < 4; ++i) qr[i] = *(const float4*)&bufA[tt + i][d];
#pragma unroll
        for (int r = 0; r < 4; ++r) sr[r] = *(const float4*)&Sp[(d + r) * DD + e0];
        const float4 z4 = *(const float4*)&zp[d];
#pragma unroll
        for (int i = 0; i < 4; ++i) {
            const float4 qv = qr[i];
            o[i][0] += qv.x * sr[0].x + qv.y * sr[1].x + qv.z * sr[2].x + qv.w * sr[3].x;
            o[i][1] += qv.x * sr[0].y + qv.y * sr[1].y + qv.z * sr[2].y + qv.w * sr[3].y;
            o[i][2] += qv.x * sr[0].z + qv.y * sr[1].z + qv.z * sr[2].z + qv.w * sr[3].z;
            o[i][3] += qv.x * sr[0].w + qv.y * sr[1].w + qv.z * sr[2].w + qv.w * sr[3].w;
            dint[i] += qv.x * z4.x + qv.y * z4.y + qv.z * z4.z + qv.w * z4.w;
        }
    }

    __syncthreads();
#pragma unroll
    for (int w = 0; w < 4; ++w) {
        const int idx = tid + (w << 8);
        *(float4*)&bufA[idx >> 4][(idx & 15) << 2] = vreg[w];
    }
    __syncthreads();

    const int nq = (tt >> 2) + 1;
    for (int sq = 0; sq < nq; ++sq) {
        float4 ar[4];
#pragma unroll
        for (int i = 0; i < 4; ++i) ar[i] = *(const float4*)&bufB[tt + i][sq << 2];
#pragma unroll
        for (int ss = 0; ss < 4; ++ss) {
            const float4 vv = *(const float4*)&bufA[(sq << 2) + ss][e0];
#pragma unroll
            for (int i = 0; i < 4; ++i) {
                const float av = F4C(ar[i], ss);
                o[i][0] += av * vv.x; o[i][1] += av * vv.y;
                o[i][2] += av * vv.z; o[i][3] += av * vv.w;
            }
        }
    }

#pragma unroll
    for (int i = 0; i < 4; ++i) {
        const float den = dint[i] + den4[i] + 1e-6f;
        const float inv = 1.0f / den;
        const int g = (((b * TT + t0 + tt + i) * HH + h) << 6) + e0;
        *(float4*)(O + g) = make_float4(o[i][0] * inv, o[i][1] * inv,
                                        o[i][2] * inv, o[i][3] * inv);
    }
}

extern "C" void kernel_launch(void* const* d_in, const int* in_sizes, int n_in,
                              void* d_out, int out_size, void* d_ws, size_t ws_size,
                              hipStream_t stream) {
    const float* q = (const float*)d_in[0];
    const float* k = (const float*)d_in[1];
    const float* v = (const float*)d_in[2];
    float* out = (float*)d_out;

    float* wsS = (float*)d_ws;                       // NCH * 64*64 floats (16.8 MB)
    float* wsZ = wsS + (size_t)NCH * DD * DD;        // NCH * 64 floats   (256 KB)

    void* args[] = {(void*)&q, (void*)&k, (void*)&v,
                    (void*)&wsS, (void*)&wsZ, (void*)&out};
    hipError_t st = hipLaunchCooperativeKernel((const void*)k_fused, dim3(NCH),
                                               dim3(256), args, 0, stream);
    if (st != hipSuccess) {
        // deterministic fallback: round-3 proven pipeline
        k_state<<<NCH, 256, 0, stream>>>(k, v, wsS, wsZ);
        k_scan<<<520, 256, 0, stream>>>(wsS, wsZ);
        k_out<<<NCH, 256, 0, stream>>>(q, k, v, wsS, wsZ, out);
    }
}

// Round 6
// 144.889 us; speedup vs baseline: 3.9760x; 3.9760x over previous
//
#include <hip/hip_runtime.h>

// Causal linear attention (ELU+1), chunked prefix-scan, 3-kernel pipeline.
// Shapes: q,k,v,out = [B=2, T=2048, H=16, D=64] fp32, layout [B,T,H,D].
//
//   out_t = phi(q_t) . S_t / (phi(q_t) . z_t + EPS)
//   S_t = sum_{s<=t} phi(k_s)^T v_s,  z_t = sum_{s<=t} phi(k_s)
//
// R5 lessons: cooperative grid.sync costs ~200+ us/barrier on MI355X (8 XCDs)
// -> fused single kernel is 3.4x SLOWER than 3 dispatches. Stay multi-kernel.
// k_out's R3 defect was LDS=51.7KB -> 3 blocks/CU + 33% tail; dropping the
// S_prev LDS stage (read from global, L1/L2-resident) gives 35.3KB -> exactly
// 4 blocks/CU x 256 CU = 1024 blocks, one round.

#define BQ 2
#define TT 2048
#define HH 16
#define DD 64
#define CC 64
#define NC (TT / CC)      // 32 chunks per (b,h)
#define BH (BQ * HH)      // 32
#define NCH (BH * NC)     // 1024 chunk-blocks
#define LDP 68            // LDS row stride (floats)

#define F4C(v, i) ((i) == 0 ? (v).x : (i) == 1 ? (v).y : (i) == 2 ? (v).z : (v).w)

__device__ __forceinline__ float phi_f(float x) {
    return x > 0.f ? x + 1.f : __expf(x);   // elu(x)+1
}

// ---------------- Phase 1: per-chunk state deltas ----------------
__global__ __launch_bounds__(256, 4) void k_state(const float* __restrict__ K,
                                                  const float* __restrict__ V,
                                                  float* __restrict__ wsS,
                                                  float* __restrict__ wsZ) {
    __shared__ float pk[CC][LDP];
    __shared__ float pv[CC][LDP];

    const int cid = blockIdx.x;
    const int bh = cid / NC, c = cid % NC;
    const int b = bh / HH, h = bh % HH;
    const int t0 = c * CC;
    const int tid = threadIdx.x;

#pragma unroll
    for (int w = 0; w < 4; ++w) {
        const int idx = tid + (w << 8);
        const int r = idx >> 4, q4 = (idx & 15) << 2;
        const int g = (((b * TT + t0 + r) * HH + h) << 6) + q4;
        float4 kv = *(const float4*)(K + g);
        kv.x = phi_f(kv.x); kv.y = phi_f(kv.y); kv.z = phi_f(kv.z); kv.w = phi_f(kv.w);
        *(float4*)&pk[r][q4] = kv;
        *(float4*)&pv[r][q4] = *(const float4*)(V + g);
    }
    __syncthreads();

    const int d0 = (tid >> 4) << 2;
    const int e0 = (tid & 15) << 2;
    float acc[4][4] = {};
    float zac[4] = {};
#pragma unroll 8
    for (int t = 0; t < CC; ++t) {
        const float4 a = *(const float4*)&pk[t][d0];
        const float4 vb = *(const float4*)&pv[t][e0];
        acc[0][0] += a.x * vb.x; acc[0][1] += a.x * vb.y; acc[0][2] += a.x * vb.z; acc[0][3] += a.x * vb.w;
        acc[1][0] += a.y * vb.x; acc[1][1] += a.y * vb.y; acc[1][2] += a.y * vb.z; acc[1][3] += a.y * vb.w;
        acc[2][0] += a.z * vb.x; acc[2][1] += a.z * vb.y; acc[2][2] += a.z * vb.z; acc[2][3] += a.z * vb.w;
        acc[3][0] += a.w * vb.x; acc[3][1] += a.w * vb.y; acc[3][2] += a.w * vb.z; acc[3][3] += a.w * vb.w;
        zac[0] += a.x; zac[1] += a.y; zac[2] += a.z; zac[3] += a.w;
    }

    float* S = wsS + (size_t)cid * (DD * DD);
#pragma unroll
    for (int i = 0; i < 4; ++i)
        *(float4*)(S + (d0 + i) * DD + e0) =
            make_float4(acc[i][0], acc[i][1], acc[i][2], acc[i][3]);
    if (e0 == 0)
        *(float4*)(wsZ + cid * DD + d0) = make_float4(zac[0], zac[1], zac[2], zac[3]);
}

// ---------------- Phase 2: exclusive prefix over chunks ----------------
__global__ __launch_bounds__(256) void k_scan(float* __restrict__ wsS,
                                              float* __restrict__ wsZ) {
    const int blk = blockIdx.x, tid = threadIdx.x;
    if (blk < 512) {                       // S: 32 bh * 16 segments of 256 elems
        const int bh = blk >> 4;
        const int off = ((blk & 15) << 8) + tid;
        float* p = wsS + (size_t)bh * NC * (DD * DD) + off;
        float run = 0.f;
#pragma unroll
        for (int c = 0; c < NC; ++c) {
            const float d = p[(size_t)c * (DD * DD)];
            p[(size_t)c * (DD * DD)] = run;
            run += d;
        }
    } else {                               // z: 32 bh * 64 elems, 8 blocks
        const int zi = ((blk - 512) << 8) + tid;
        const int bh = zi >> 6, d = zi & 63;
        float* p = wsZ + bh * NC * DD + d;
        float run = 0.f;
#pragma unroll
        for (int c = 0; c < NC; ++c) {
            const float dv = p[c * DD];
            p[c * DD] = run;
            run += dv;
        }
    }
}

// ---------------- Phase 3: outputs (S_prev from global; 35.3KB LDS) ----------------
__global__ __launch_bounds__(256, 4) void k_out(const float* __restrict__ Q,
                                                const float* __restrict__ K,
                                                const float* __restrict__ V,
                                                const float* __restrict__ wsS,
                                                const float* __restrict__ wsZ,
                                                float* __restrict__ O) {
    __shared__ float bufA[CC][LDP];   // phi(Q), later V
    __shared__ float bufB[CC][LDP];   // phi(K), later scores
    __shared__ float zp[DD];

    const int cid = blockIdx.x;
    const int bh = cid / NC, c = cid % NC;
    const int b = bh / HH, h = bh % HH;
    const int t0 = c * CC;
    const int tid = threadIdx.x;

    float4 vreg[4];                    // V staged in regs, LDS-written late (T14)
#pragma unroll
    for (int w = 0; w < 4; ++w) {
        const int idx = tid + (w << 8);
        const int r = idx >> 4, q4 = (idx & 15) << 2;
        const int g = (((b * TT + t0 + r) * HH + h) << 6) + q4;
        vreg[w] = *(const float4*)(V + g);
        float4 qv = *(const float4*)(Q + g);
        qv.x = phi_f(qv.x); qv.y = phi_f(qv.y); qv.z = phi_f(qv.z); qv.w = phi_f(qv.w);
        *(float4*)&bufA[r][q4] = qv;
        float4 kv = *(const float4*)(K + g);
        kv.x = phi_f(kv.x); kv.y = phi_f(kv.y); kv.z = phi_f(kv.z); kv.w = phi_f(kv.w);
        *(float4*)&bufB[r][q4] = kv;
    }
    if (tid < 16) ((float4*)zp)[tid] = ((const float4*)(wsZ + cid * DD))[tid];
    __syncthreads();

    const int tt = (tid >> 4) << 2;   // output row-quad
    const int e0 = (tid & 15) << 2;   // output col-quad / score col-quad

    // ---- Pass A: scores a[i][j] = phiQ[tt+i] . phiK[e0+j]
    float den4[4];
    {
        float a[4][4] = {};
#pragma unroll 4
        for (int d = 0; d < DD; d += 4) {
            float4 qr[4], kr[4];
#pragma unroll
            for (int i = 0; i < 4; ++i) qr[i] = *(const float4*)&bufA[tt + i][d];
#pragma unroll
            for (int j = 0; j < 4; ++j) kr[j] = *(const float4*)&bufB[e0 + j][d];
#pragma unroll
            for (int i = 0; i < 4; ++i)
#pragma unroll
                for (int j = 0; j < 4; ++j)
                    a[i][j] += qr[i].x * kr[j].x + qr[i].y * kr[j].y +
                               qr[i].z * kr[j].z + qr[i].w * kr[j].w;
        }
#pragma unroll
        for (int i = 0; i < 4; ++i) {
#pragma unroll
            for (int j = 0; j < 4; ++j)
                if (e0 + j > tt + i) a[i][j] = 0.f;
            den4[i] = a[i][0] + a[i][1] + a[i][2] + a[i][3];
        }
#pragma unroll
        for (int m = 1; m < 16; m <<= 1)
#pragma unroll
            for (int i = 0; i < 4; ++i)
                den4[i] += __shfl_xor(den4[i], m, 64);

        __syncthreads();   // all threads done reading phiK from bufB
#pragma unroll
        for (int i = 0; i < 4; ++i)
            *(float4*)&bufB[tt + i][e0] =
                make_float4(a[i][0], a[i][1], a[i][2], a[i][3]);
    }

    // ---- Inter-chunk: o = phiQ @ S_prev (S_prev from GLOBAL), dint = phiQ.z_prev
    float o[4][4] = {};
    float dint[4] = {};
    {
        const float* Sg = wsS + (size_t)cid * (DD * DD);
#pragma unroll 4
        for (int d = 0; d < DD; d += 4) {
            float4 qr[4], sr[4];
#pragma unroll
            for (int i = 0; i < 4; ++i) qr[i] = *(const float4*)&bufA[tt + i][d];
#pragma unroll
            for (int r = 0; r < 4; ++r)
                sr[r] = *(const float4*)(Sg + (d + r) * DD + e0);
            const float4 z4 = *(const float4*)&zp[d];
#pragma unroll
            for (int i = 0; i < 4; ++i) {
                const float4 qv = qr[i];
                o[i][0] += qv.x * sr[0].x + qv.y * sr[1].x + qv.z * sr[2].x + qv.w * sr[3].x;
                o[i][1] += qv.x * sr[0].y + qv.y * sr[1].y + qv.z * sr[2].y + qv.w * sr[3].y;
                o[i][2] += qv.x * sr[0].z + qv.y * sr[1].z + qv.z * sr[2].z + qv.w * sr[3].z;
                o[i][3] += qv.x * sr[0].w + qv.y * sr[1].w + qv.z * sr[2].w + qv.w * sr[3].w;
                dint[i] += qv.x * z4.x + qv.y * z4.y + qv.z * z4.z + qv.w * z4.w;
            }
        }
    }

    __syncthreads();   // score-writes visible; everyone done reading phiQ
#pragma unroll
    for (int w = 0; w < 4; ++w) {
        const int idx = tid + (w << 8);
        *(float4*)&bufA[idx >> 4][(idx & 15) << 2] = vreg[w];
    }
    __syncthreads();

    // ---- Pass B: o += tril(A) @ V
    const int nq = (tt >> 2) + 1;
    for (int sq = 0; sq < nq; ++sq) {
        float4 ar[4];
#pragma unroll
        for (int i = 0; i < 4; ++i) ar[i] = *(const float4*)&bufB[tt + i][sq << 2];
#pragma unroll
        for (int ss = 0; ss < 4; ++ss) {
            const float4 vv = *(const float4*)&bufA[(sq << 2) + ss][e0];
#pragma unroll
            for (int i = 0; i < 4; ++i) {
                const float av = F4C(ar[i], ss);
                o[i][0] += av * vv.x; o[i][1] += av * vv.y;
                o[i][2] += av * vv.z; o[i][3] += av * vv.w;
            }
        }
    }

    // ---- Epilogue
#pragma unroll
    for (int i = 0; i < 4; ++i) {
        const float den = dint[i] + den4[i] + 1e-6f;
        const float inv = 1.0f / den;
        const int g = (((b * TT + t0 + tt + i) * HH + h) << 6) + e0;
        *(float4*)(O + g) = make_float4(o[i][0] * inv, o[i][1] * inv,
                                        o[i][2] * inv, o[i][3] * inv);
    }
}

extern "C" void kernel_launch(void* const* d_in, const int* in_sizes, int n_in,
                              void* d_out, int out_size, void* d_ws, size_t ws_size,
                              hipStream_t stream) {
    const float* q = (const float*)d_in[0];
    const float* k = (const float*)d_in[1];
    const float* v = (const float*)d_in[2];
    float* out = (float*)d_out;

    float* wsS = (float*)d_ws;                       // NCH * 64*64 floats (16.8 MB)
    float* wsZ = wsS + (size_t)NCH * DD * DD;        // NCH * 64 floats   (256 KB)

    k_state<<<NCH, 256, 0, stream>>>(k, v, wsS, wsZ);
    k_scan<<<520, 256, 0, stream>>>(wsS, wsZ);
    k_out<<<NCH, 256, 0, stream>>>(q, k, v, wsS, wsZ, out);
}

// Round 8
// 115.132 us; speedup vs baseline: 5.0036x; 1.2585x over previous
//
#include <hip/hip_runtime.h>

// Causal linear attention (ELU+1), chunked prefix-scan, 3-kernel pipeline,
// matmuls on bf16 MFMA (v_mfma_f32_16x16x32_bf16), fp32 accumulate.
// Shapes: q,k,v,out = [B=2, T=2048, H=16, D=64] fp32, layout [B,T,H,D].
//
// R6 lesson: fp32 VALU version is instruction-bound (VALUBusy 41%, MfmaUtil 0,
// k_out pinned at 46 us regardless of LDS/occupancy). Threshold 6.9e-2 gives
// bf16 plenty of headroom (fp32 path measured absmax 3.9e-3).
// R7: +16B alignment on LDS ushort tiles (b128 read safety); logic unchanged.
//
// Fragment conventions (gfx950 16x16x32 bf16):
//   A-frag: lane = m + 16*kblk holds A[m][kblk*8+i]        (read ROW m of tile)
//   B-frag: lane = n + 16*kblk holds B[kblk*8+i][n]        (read ROW n of B^T tile)
//   C/D:    lane holds D[(lane>>4)*4+j][lane&15]           (verified m89)
// Every operand is staged so the needed matrix is ROW-major in LDS:
//   scores = phiQ rows x phiK rows (as B^T)      -> Qb, Kb natural
//   PV     = A rows    x V^T rows                -> Vt transposed stage
//   inter  = phiQ rows x S^T rows                -> k_state emits S^T to ws
//   dS^T   = V^T rows  x phiK^T rows             -> Vt, Kt transposed stages

#define BQ 2
#define TT 2048
#define HH 16
#define DD 64
#define CC 64
#define NC (TT / CC)      // 32 chunks per (b,h)
#define BH (BQ * HH)      // 32
#define NCH (BH * NC)     // 1024 chunk-blocks
#define LDU 72            // ushort stride: 144B rows (16B-aligned, bank-skewed)

typedef __attribute__((ext_vector_type(8))) short short8;
typedef __attribute__((ext_vector_type(4))) float f32x4;

__device__ __forceinline__ float phi_f(float x) {
    return x > 0.f ? x + 1.f : __expf(x);   // elu(x)+1
}
__device__ __forceinline__ unsigned short f2bf(float f) {   // fp32 -> bf16 RNE
    unsigned int u = __float_as_uint(f);
    u += 0x7FFFu + ((u >> 16) & 1u);
    return (unsigned short)(u >> 16);
}
__device__ __forceinline__ float bf2f(unsigned short s) {
    return __uint_as_float(((unsigned int)s) << 16);
}

// ---------------- Phase 1: per-chunk state deltas (emits dS^T) ----------------
__global__ __launch_bounds__(256, 4) void k_state(const float* __restrict__ K,
                                                  const float* __restrict__ V,
                                                  float* __restrict__ wsS,
                                                  float* __restrict__ wsZ) {
    __shared__ __align__(16) unsigned short Kt[DD][LDU];   // phiK^T: Kt[d][t]
    __shared__ __align__(16) unsigned short Vt[DD][LDU];   // V^T:    Vt[e][t]

    const int cid = blockIdx.x;
    const int bh = cid / NC, c = cid % NC;
    const int b = bh / HH, h = bh % HH;
    const int t0 = c * CC;
    const int tid = threadIdx.x;

#pragma unroll
    for (int w = 0; w < 4; ++w) {
        const int idx = tid + (w << 8);
        const int r = idx >> 4, q4 = (idx & 15) << 2;   // r = t-row, q4 = d/e quad
        const int g = (((b * TT + t0 + r) * HH + h) << 6) + q4;
        const float4 kv = *(const float4*)(K + g);
        Kt[q4 + 0][r] = f2bf(phi_f(kv.x));
        Kt[q4 + 1][r] = f2bf(phi_f(kv.y));
        Kt[q4 + 2][r] = f2bf(phi_f(kv.z));
        Kt[q4 + 3][r] = f2bf(phi_f(kv.w));
        const float4 vv = *(const float4*)(V + g);
        Vt[q4 + 0][r] = f2bf(vv.x);
        Vt[q4 + 1][r] = f2bf(vv.y);
        Vt[q4 + 2][r] = f2bf(vv.z);
        Vt[q4 + 3][r] = f2bf(vv.w);
    }
    __syncthreads();

    const int wid = tid >> 6, lane = tid & 63;
    const int rg = lane >> 4, cl = lane & 15;

    // dS^T[e][d] = sum_t V[t][e] * phiK[t][d] ; wave wid owns e-band 16*wid..+15
    f32x4 zero4 = {0.f, 0.f, 0.f, 0.f};
    f32x4 acc[4] = {zero4, zero4, zero4, zero4};
#pragma unroll
    for (int kk = 0; kk < 2; ++kk) {
        const short8 a = *(const short8*)&Vt[16 * wid + cl][kk * 32 + rg * 8];
#pragma unroll
        for (int nt = 0; nt < 4; ++nt) {
            const short8 bb = *(const short8*)&Kt[16 * nt + cl][kk * 32 + rg * 8];
            acc[nt] = __builtin_amdgcn_mfma_f32_16x16x32_bf16(a, bb, acc[nt], 0, 0, 0);
        }
    }

    // z[d] = sum_t phiK[t][d]  (wave 0, one row of Kt per thread)
    if (tid < DD) {
        float s = 0.f;
#pragma unroll
        for (int tb = 0; tb < 8; ++tb) {
            const short8 v = *(const short8*)&Kt[tid][tb * 8];
#pragma unroll
            for (int i = 0; i < 8; ++i) s += bf2f((unsigned short)v[i]);
        }
        wsZ[cid * DD + tid] = s;
    }

    // store dS^T (layout [e][d])
    float* S = wsS + (size_t)cid * (DD * DD);
#pragma unroll
    for (int nt = 0; nt < 4; ++nt)
#pragma unroll
        for (int j = 0; j < 4; ++j)
            S[(16 * wid + 4 * rg + j) * DD + 16 * nt + cl] = acc[nt][j];
}

// ---------------- Phase 2: exclusive prefix over chunks ----------------
__global__ __launch_bounds__(256) void k_scan(float* __restrict__ wsS,
                                              float* __restrict__ wsZ) {
    const int blk = blockIdx.x, tid = threadIdx.x;
    if (blk < 512) {
        const int bh = blk >> 4;
        const int off = ((blk & 15) << 8) + tid;
        float* p = wsS + (size_t)bh * NC * (DD * DD) + off;
        float run = 0.f;
#pragma unroll
        for (int c = 0; c < NC; ++c) {
            const float d = p[(size_t)c * (DD * DD)];
            p[(size_t)c * (DD * DD)] = run;
            run += d;
        }
    } else {
        const int zi = ((blk - 512) << 8) + tid;
        const int bh = zi >> 6, d = zi & 63;
        float* p = wsZ + bh * NC * DD + d;
        float run = 0.f;
#pragma unroll
        for (int c = 0; c < NC; ++c) {
            const float dv = p[c * DD];
            p[c * DD] = run;
            run += dv;
        }
    }
}

// ---------------- Phase 3: outputs ----------------
__global__ __launch_bounds__(256, 4) void k_out(const float* __restrict__ Q,
                                                const float* __restrict__ K,
                                                const float* __restrict__ V,
                                                const float* __restrict__ wsS,
                                                const float* __restrict__ wsZ,
                                                float* __restrict__ O) {
    __shared__ __align__(16) unsigned short Qb[CC][LDU];   // phiQ rows
    __shared__ __align__(16) unsigned short Kb[CC][LDU];   // phiK rows; later masked scores
    __shared__ __align__(16) unsigned short Vt[DD][LDU];   // V^T rows (e-major)
    __shared__ __align__(16) unsigned short St[DD][LDU];   // S_prev^T rows (e-major)
    __shared__ float zp[DD];

    const int cid = blockIdx.x;
    const int bh = cid / NC, c = cid % NC;
    const int b = bh / HH, h = bh % HH;
    const int t0 = c * CC;
    const int tid = threadIdx.x;

#pragma unroll
    for (int w = 0; w < 4; ++w) {
        const int idx = tid + (w << 8);
        const int r = idx >> 4, q4 = (idx & 15) << 2;
        const int g = (((b * TT + t0 + r) * HH + h) << 6) + q4;
        float4 qv = *(const float4*)(Q + g);
        ushort4 us;
        us.x = f2bf(phi_f(qv.x)); us.y = f2bf(phi_f(qv.y));
        us.z = f2bf(phi_f(qv.z)); us.w = f2bf(phi_f(qv.w));
        *(ushort4*)&Qb[r][q4] = us;
        float4 kv = *(const float4*)(K + g);
        us.x = f2bf(phi_f(kv.x)); us.y = f2bf(phi_f(kv.y));
        us.z = f2bf(phi_f(kv.z)); us.w = f2bf(phi_f(kv.w));
        *(ushort4*)&Kb[r][q4] = us;
        const float4 vv = *(const float4*)(V + g);
        Vt[q4 + 0][r] = f2bf(vv.x);
        Vt[q4 + 1][r] = f2bf(vv.y);
        Vt[q4 + 2][r] = f2bf(vv.z);
        Vt[q4 + 3][r] = f2bf(vv.w);
        const float4 sv = *(const float4*)(wsS + (size_t)cid * (DD * DD) + r * DD + q4);
        us.x = f2bf(sv.x); us.y = f2bf(sv.y); us.z = f2bf(sv.z); us.w = f2bf(sv.w);
        *(ushort4*)&St[r][q4] = us;
    }
    if (tid < 16) ((float4*)zp)[tid] = ((const float4*)(wsZ + cid * DD))[tid];
    __syncthreads();

    const int wid = tid >> 6, lane = tid & 63;
    const int rg = lane >> 4, cl = lane & 15;
    f32x4 zero4 = {0.f, 0.f, 0.f, 0.f};

    // ---- scores: D[q][kv], wave wid owns q-band 16*wid..+15; only nt <= wid
    f32x4 sc[4] = {zero4, zero4, zero4, zero4};
#pragma unroll
    for (int kk = 0; kk < 2; ++kk) {
        const short8 a = *(const short8*)&Qb[16 * wid + cl][kk * 32 + rg * 8];
        for (int nt = 0; nt <= wid; ++nt) {
            const short8 bb = *(const short8*)&Kb[16 * nt + cl][kk * 32 + rg * 8];
            sc[nt] = __builtin_amdgcn_mfma_f32_16x16x32_bf16(a, bb, sc[nt], 0, 0, 0);
        }
    }

    // ---- causal mask + row-sum den4; dint = phiQ . z_prev (lane-sliced)
    float den4[4], dint[4];
    const float4 zq = *(const float4*)&zp[4 * cl];
#pragma unroll
    for (int j = 0; j < 4; ++j) {
        const int qrow = 16 * wid + 4 * rg + j;
        float s = 0.f;
        for (int nt = 0; nt <= wid; ++nt) {
            if (16 * nt + cl > qrow) sc[nt][j] = 0.f;
            s += sc[nt][j];
        }
        den4[j] = s;
        const ushort4 qv = *(const ushort4*)&Qb[qrow][4 * cl];
        dint[j] = bf2f(qv.x) * zq.x + bf2f(qv.y) * zq.y +
                  bf2f(qv.z) * zq.z + bf2f(qv.w) * zq.w;
    }
#pragma unroll
    for (int m = 1; m < 16; m <<= 1)
#pragma unroll
        for (int j = 0; j < 4; ++j) {
            den4[j] += __shfl_xor(den4[j], m, 64);
            dint[j] += __shfl_xor(dint[j], m, 64);
        }

    // ---- inter-chunk: o = phiQ @ S_prev  (B = S^T rows)
    f32x4 oa[4] = {zero4, zero4, zero4, zero4};
#pragma unroll
    for (int kk = 0; kk < 2; ++kk) {
        const short8 a = *(const short8*)&Qb[16 * wid + cl][kk * 32 + rg * 8];
#pragma unroll
        for (int nt = 0; nt < 4; ++nt) {
            const short8 bb = *(const short8*)&St[16 * nt + cl][kk * 32 + rg * 8];
            oa[nt] = __builtin_amdgcn_mfma_f32_16x16x32_bf16(a, bb, oa[nt], 0, 0, 0);
        }
    }

    __syncthreads();   // everyone done reading Kb (scores)
    // write masked scores as bf16 into Kb; zeros for nt > wid
#pragma unroll
    for (int nt = 0; nt < 4; ++nt)
#pragma unroll
        for (int j = 0; j < 4; ++j)
            Kb[16 * wid + 4 * rg + j][16 * nt + cl] =
                (nt <= wid) ? f2bf(sc[nt][j]) : (unsigned short)0;
    __syncthreads();

    // ---- PV: o += A @ V   (A rows from Kb, B = V^T rows); kv <= 16*wid+15
    const int kkmax = (wid >= 2) ? 2 : 1;
    for (int kk = 0; kk < kkmax; ++kk) {
        const short8 a = *(const short8*)&Kb[16 * wid + cl][kk * 32 + rg * 8];
#pragma unroll
        for (int nt = 0; nt < 4; ++nt) {
            const short8 bb = *(const short8*)&Vt[16 * nt + cl][kk * 32 + rg * 8];
            oa[nt] = __builtin_amdgcn_mfma_f32_16x16x32_bf16(a, bb, oa[nt], 0, 0, 0);
        }
    }

    // ---- epilogue: divide, store (16-lane groups hit 64B segments)
#pragma unroll
    for (int j = 0; j < 4; ++j) {
        const int qrow = 16 * wid + 4 * rg + j;
        const float inv = 1.0f / (den4[j] + dint[j] + 1e-6f);
        const int gbase = (((b * TT + t0 + qrow) * HH + h) << 6);
#pragma unroll
        for (int nt = 0; nt < 4; ++nt)
            O[gbase + 16 * nt + cl] = oa[nt][j] * inv;
    }
}

extern "C" void kernel_launch(void* const* d_in, const int* in_sizes, int n_in,
                              void* d_out, int out_size, void* d_ws, size_t ws_size,
                              hipStream_t stream) {
    const float* q = (const float*)d_in[0];
    const float* k = (const float*)d_in[1];
    const float* v = (const float*)d_in[2];
    float* out = (float*)d_out;

    float* wsS = (float*)d_ws;                       // NCH * 64*64 floats (16.8 MB), holds S^T
    float* wsZ = wsS + (size_t)NCH * DD * DD;        // NCH * 64 floats   (256 KB)

    k_state<<<NCH, 256, 0, stream>>>(k, v, wsS, wsZ);
    k_scan<<<520, 256, 0, stream>>>(wsS, wsZ);
    k_out<<<NCH, 256, 0, stream>>>(q, k, v, wsS, wsZ, out);
}

// Round 9
// 109.372 us; speedup vs baseline: 5.2672x; 1.0527x over previous
//
#include <hip/hip_runtime.h>

// Causal linear attention (ELU+1), chunked prefix-scan, 3-kernel pipeline,
// matmuls on bf16 MFMA (v_mfma_f32_16x16x32_bf16), fp32 accumulate.
// Shapes: q,k,v,out = [B=2, T=2048, H=16, D=64] fp32, layout [B,T,H,D].
//
// R8 state: 115 us total, absmax 0.0156 (thr 0.0688); all kernels < 41.6 us
// (top-5 = harness ws-poison fills). Scan suspected dominant: 32 serial
// dependent strided loads/thread.
// R9 changes: (1) k_scan batch-loads all 32 deltas to regs (1 latency exposure),
// (2) S stored bf16 in ws (k_out quantizes to bf16 anyway) -> half traffic,
// (3) k_out St stage = raw ushort4 copy.
//
// Fragment conventions (gfx950 16x16x32 bf16):
//   A-frag: lane = m + 16*kblk holds A[m][kblk*8+i]        (read ROW m of tile)
//   B-frag: lane = n + 16*kblk holds B[kblk*8+i][n]        (read ROW n of B^T tile)
//   C/D:    lane holds D[(lane>>4)*4+j][lane&15]           (verified m89)

#define BQ 2
#define TT 2048
#define HH 16
#define DD 64
#define CC 64
#define NC (TT / CC)      // 32 chunks per (b,h)
#define BH (BQ * HH)      // 32
#define NCH (BH * NC)     // 1024 chunk-blocks
#define LDU 72            // ushort stride: 144B rows (16B-aligned, bank-skewed)

typedef __attribute__((ext_vector_type(8))) short short8;
typedef __attribute__((ext_vector_type(4))) float f32x4;

__device__ __forceinline__ float phi_f(float x) {
    return x > 0.f ? x + 1.f : __expf(x);   // elu(x)+1
}
__device__ __forceinline__ unsigned short f2bf(float f) {   // fp32 -> bf16 RNE
    unsigned int u = __float_as_uint(f);
    u += 0x7FFFu + ((u >> 16) & 1u);
    return (unsigned short)(u >> 16);
}
__device__ __forceinline__ float bf2f(unsigned short s) {
    return __uint_as_float(((unsigned int)s) << 16);
}

// ---------------- Phase 1: per-chunk state deltas (emits dS^T as bf16) ----------------
__global__ __launch_bounds__(256, 4) void k_state(const float* __restrict__ K,
                                                  const float* __restrict__ V,
                                                  unsigned short* __restrict__ wsSh,
                                                  float* __restrict__ wsZ) {
    __shared__ __align__(16) unsigned short Kt[DD][LDU];   // phiK^T: Kt[d][t]
    __shared__ __align__(16) unsigned short Vt[DD][LDU];   // V^T:    Vt[e][t]

    const int cid = blockIdx.x;
    const int bh = cid / NC, c = cid % NC;
    const int b = bh / HH, h = bh % HH;
    const int t0 = c * CC;
    const int tid = threadIdx.x;

#pragma unroll
    for (int w = 0; w < 4; ++w) {
        const int idx = tid + (w << 8);
        const int r = idx >> 4, q4 = (idx & 15) << 2;   // r = t-row, q4 = d/e quad
        const int g = (((b * TT + t0 + r) * HH + h) << 6) + q4;
        const float4 kv = *(const float4*)(K + g);
        Kt[q4 + 0][r] = f2bf(phi_f(kv.x));
        Kt[q4 + 1][r] = f2bf(phi_f(kv.y));
        Kt[q4 + 2][r] = f2bf(phi_f(kv.z));
        Kt[q4 + 3][r] = f2bf(phi_f(kv.w));
        const float4 vv = *(const float4*)(V + g);
        Vt[q4 + 0][r] = f2bf(vv.x);
        Vt[q4 + 1][r] = f2bf(vv.y);
        Vt[q4 + 2][r] = f2bf(vv.z);
        Vt[q4 + 3][r] = f2bf(vv.w);
    }
    __syncthreads();

    const int wid = tid >> 6, lane = tid & 63;
    const int rg = lane >> 4, cl = lane & 15;

    // dS^T[e][d] = sum_t V[t][e] * phiK[t][d] ; wave wid owns e-band 16*wid..+15
    f32x4 zero4 = {0.f, 0.f, 0.f, 0.f};
    f32x4 acc[4] = {zero4, zero4, zero4, zero4};
#pragma unroll
    for (int kk = 0; kk < 2; ++kk) {
        const short8 a = *(const short8*)&Vt[16 * wid + cl][kk * 32 + rg * 8];
#pragma unroll
        for (int nt = 0; nt < 4; ++nt) {
            const short8 bb = *(const short8*)&Kt[16 * nt + cl][kk * 32 + rg * 8];
            acc[nt] = __builtin_amdgcn_mfma_f32_16x16x32_bf16(a, bb, acc[nt], 0, 0, 0);
        }
    }

    // z[d] = sum_t phiK[t][d]  (tid<64: one row of Kt per thread)
    if (tid < DD) {
        float s = 0.f;
#pragma unroll
        for (int tb = 0; tb < 8; ++tb) {
            const short8 v = *(const short8*)&Kt[tid][tb * 8];
#pragma unroll
            for (int i = 0; i < 8; ++i) s += bf2f((unsigned short)v[i]);
        }
        wsZ[cid * DD + tid] = s;
    }

    // store dS^T (layout [e][d], bf16)
    unsigned short* S = wsSh + (size_t)cid * (DD * DD);
#pragma unroll
    for (int nt = 0; nt < 4; ++nt)
#pragma unroll
        for (int j = 0; j < 4; ++j)
            S[(16 * wid + 4 * rg + j) * DD + 16 * nt + cl] = f2bf(acc[nt][j]);
}

// ---------------- Phase 2: exclusive prefix over chunks (batched loads) ----------------
__global__ __launch_bounds__(256) void k_scan(unsigned short* __restrict__ wsSh,
                                              float* __restrict__ wsZ) {
    const int blk = blockIdx.x, tid = threadIdx.x;
    if (blk < 256) {
        // S: 32 bh * 2048 dword-columns (2 bf16 each); one column per thread
        const int col = (blk << 8) + tid;          // 0..65535
        const int bh = col >> 11;                  // /2048
        unsigned int* base =
            (unsigned int*)(wsSh + (size_t)bh * NC * (DD * DD)) + (col & 2047);
        unsigned int vals[NC];
#pragma unroll
        for (int c = 0; c < NC; ++c) vals[c] = base[c * (DD * DD / 2)];
        float r0 = 0.f, r1 = 0.f;
#pragma unroll
        for (int c = 0; c < NC; ++c) {
            const unsigned int v = vals[c];
            base[c * (DD * DD / 2)] =
                (unsigned int)f2bf(r0) | ((unsigned int)f2bf(r1) << 16);
            r0 += bf2f((unsigned short)(v & 0xffffu));
            r1 += bf2f((unsigned short)(v >> 16));
        }
    } else {
        // z: 32 bh * 64 columns, fp32; blocks 256..263
        const int zi = ((blk - 256) << 8) + tid;   // 0..2047
        const int bh = zi >> 6, d = zi & 63;
        float* p = wsZ + (size_t)bh * NC * DD + d;
        float vals[NC];
#pragma unroll
        for (int c = 0; c < NC; ++c) vals[c] = p[c * DD];
        float run = 0.f;
#pragma unroll
        for (int c = 0; c < NC; ++c) {
            p[c * DD] = run;
            run += vals[c];
        }
    }
}

// ---------------- Phase 3: outputs ----------------
__global__ __launch_bounds__(256, 4) void k_out(const float* __restrict__ Q,
                                                const float* __restrict__ K,
                                                const float* __restrict__ V,
                                                const unsigned short* __restrict__ wsSh,
                                                const float* __restrict__ wsZ,
                                                float* __restrict__ O) {
    __shared__ __align__(16) unsigned short Qb[CC][LDU];   // phiQ rows
    __shared__ __align__(16) unsigned short Kb[CC][LDU];   // phiK rows; later masked scores
    __shared__ __align__(16) unsigned short Vt[DD][LDU];   // V^T rows (e-major)
    __shared__ __align__(16) unsigned short St[DD][LDU];   // S_prev^T rows (e-major)
    __shared__ float zp[DD];

    const int cid = blockIdx.x;
    const int bh = cid / NC, c = cid % NC;
    const int b = bh / HH, h = bh % HH;
    const int t0 = c * CC;
    const int tid = threadIdx.x;

#pragma unroll
    for (int w = 0; w < 4; ++w) {
        const int idx = tid + (w << 8);
        const int r = idx >> 4, q4 = (idx & 15) << 2;
        const int g = (((b * TT + t0 + r) * HH + h) << 6) + q4;
        float4 qv = *(const float4*)(Q + g);
        ushort4 us;
        us.x = f2bf(phi_f(qv.x)); us.y = f2bf(phi_f(qv.y));
        us.z = f2bf(phi_f(qv.z)); us.w = f2bf(phi_f(qv.w));
        *(ushort4*)&Qb[r][q4] = us;
        float4 kv = *(const float4*)(K + g);
        us.x = f2bf(phi_f(kv.x)); us.y = f2bf(phi_f(kv.y));
        us.z = f2bf(phi_f(kv.z)); us.w = f2bf(phi_f(kv.w));
        *(ushort4*)&Kb[r][q4] = us;
        const float4 vv = *(const float4*)(V + g);
        Vt[q4 + 0][r] = f2bf(vv.x);
        Vt[q4 + 1][r] = f2bf(vv.y);
        Vt[q4 + 2][r] = f2bf(vv.z);
        Vt[q4 + 3][r] = f2bf(vv.w);
        // S_prev^T is already bf16 in ws: raw copy
        *(ushort4*)&St[r][q4] =
            *(const ushort4*)(wsSh + (size_t)cid * (DD * DD) + r * DD + q4);
    }
    if (tid < 16) ((float4*)zp)[tid] = ((const float4*)(wsZ + cid * DD))[tid];
    __syncthreads();

    const int wid = tid >> 6, lane = tid & 63;
    const int rg = lane >> 4, cl = lane & 15;
    f32x4 zero4 = {0.f, 0.f, 0.f, 0.f};

    // ---- scores: D[q][kv], wave wid owns q-band 16*wid..+15; only nt <= wid
    f32x4 sc[4] = {zero4, zero4, zero4, zero4};
#pragma unroll
    for (int kk = 0; kk < 2; ++kk) {
        const short8 a = *(const short8*)&Qb[16 * wid + cl][kk * 32 + rg * 8];
        for (int nt = 0; nt <= wid; ++nt) {
            const short8 bb = *(const short8*)&Kb[16 * nt + cl][kk * 32 + rg * 8];
            sc[nt] = __builtin_amdgcn_mfma_f32_16x16x32_bf16(a, bb, sc[nt], 0, 0, 0);
        }
    }

    // ---- causal mask + row-sum den4; dint = phiQ . z_prev (lane-sliced)
    float den4[4], dint[4];
    const float4 zq = *(const float4*)&zp[4 * cl];
#pragma unroll
    for (int j = 0; j < 4; ++j) {
        const int qrow = 16 * wid + 4 * rg + j;
        float s = 0.f;
        for (int nt = 0; nt <= wid; ++nt) {
            if (16 * nt + cl > qrow) sc[nt][j] = 0.f;
            s += sc[nt][j];
        }
        den4[j] = s;
        const ushort4 qv = *(const ushort4*)&Qb[qrow][4 * cl];
        dint[j] = bf2f(qv.x) * zq.x + bf2f(qv.y) * zq.y +
                  bf2f(qv.z) * zq.z + bf2f(qv.w) * zq.w;
    }
#pragma unroll
    for (int m = 1; m < 16; m <<= 1)
#pragma unroll
        for (int j = 0; j < 4; ++j) {
            den4[j] += __shfl_xor(den4[j], m, 64);
            dint[j] += __shfl_xor(dint[j], m, 64);
        }

    // ---- inter-chunk: o = phiQ @ S_prev  (B = S^T rows)
    f32x4 oa[4] = {zero4, zero4, zero4, zero4};
#pragma unroll
    for (int kk = 0; kk < 2; ++kk) {
        const short8 a = *(const short8*)&Qb[16 * wid + cl][kk * 32 + rg * 8];
#pragma unroll
        for (int nt = 0; nt < 4; ++nt) {
            const short8 bb = *(const short8*)&St[16 * nt + cl][kk * 32 + rg * 8];
            oa[nt] = __builtin_amdgcn_mfma_f32_16x16x32_bf16(a, bb, oa[nt], 0, 0, 0);
        }
    }

    __syncthreads();   // everyone done reading Kb (scores)
    // write masked scores as bf16 into Kb; zeros for nt > wid
#pragma unroll
    for (int nt = 0; nt < 4; ++nt)
#pragma unroll
        for (int j = 0; j < 4; ++j)
            Kb[16 * wid + 4 * rg + j][16 * nt + cl] =
                (nt <= wid) ? f2bf(sc[nt][j]) : (unsigned short)0;
    __syncthreads();

    // ---- PV: o += A @ V   (A rows from Kb, B = V^T rows); kv <= 16*wid+15
    const int kkmax = (wid >= 2) ? 2 : 1;
    for (int kk = 0; kk < kkmax; ++kk) {
        const short8 a = *(const short8*)&Kb[16 * wid + cl][kk * 32 + rg * 8];
#pragma unroll
        for (int nt = 0; nt < 4; ++nt) {
            const short8 bb = *(const short8*)&Vt[16 * nt + cl][kk * 32 + rg * 8];
            oa[nt] = __builtin_amdgcn_mfma_f32_16x16x32_bf16(a, bb, oa[nt], 0, 0, 0);
        }
    }

    // ---- epilogue: divide, store (16-lane groups hit 64B segments)
#pragma unroll
    for (int j = 0; j < 4; ++j) {
        const int qrow = 16 * wid + 4 * rg + j;
        const float inv = 1.0f / (den4[j] + dint[j] + 1e-6f);
        const int gbase = (((b * TT + t0 + qrow) * HH + h) << 6);
#pragma unroll
        for (int nt = 0; nt < 4; ++nt)
            O[gbase + 16 * nt + cl] = oa[nt][j] * inv;
    }
}

extern "C" void kernel_launch(void* const* d_in, const int* in_sizes, int n_in,
                              void* d_out, int out_size, void* d_ws, size_t ws_size,
                              hipStream_t stream) {
    const float* q = (const float*)d_in[0];
    const float* k = (const float*)d_in[1];
    const float* v = (const float*)d_in[2];
    float* out = (float*)d_out;

    float* wsZ = (float*)d_ws;                              // NCH*64 fp32 (256 KB)
    unsigned short* wsSh = (unsigned short*)(wsZ + (size_t)NCH * DD);  // NCH*4096 bf16 (8.4 MB)

    k_state<<<NCH, 256, 0, stream>>>(k, v, wsSh, wsZ);
    k_scan<<<264, 256, 0, stream>>>(wsSh, wsZ);
    k_out<<<NCH, 256, 0, stream>>>(q, k, v, wsSh, wsZ, out);
}